// Round 12
// baseline (124.639 us; speedup 1.0000x reference)
//
#include <hip/hip_runtime.h>

#define HD 512
#define B_MOL 64
#define ASV 24
#define ASU 32
#define AF 133
#define BFD 147
#define NA_SV (B_MOL*ASV)     // 1536
#define NB_SV (2*B_MOL*ASV)   // 3072
#define NA_SU (B_MOL*ASU)     // 2048
#define NB_SU (2*B_MOL*ASU)   // 4096
#define NBT (NB_SV+NB_SU)     // 7168
#define NAT (NA_SV+NA_SU)     // 3584
#define NPAIR (B_MOL*ASV*ASU) // 49152
#define KPAD 192
#define AKP 704

typedef __bf16 bf16x8 __attribute__((ext_vector_type(8)));
typedef float f32x4 __attribute__((ext_vector_type(4)));

__device__ __forceinline__ unsigned short f2bf(float f) {
  unsigned u = __builtin_bit_cast(unsigned, f);
  unsigned r = u + 0x7fffu + ((u >> 16) & 1u);
  return (unsigned short)(r >> 16);
}
__device__ __forceinline__ float bf2f(unsigned short h) {
  unsigned u = ((unsigned)h) << 16;
  return __builtin_bit_cast(float, u);
}
__device__ __forceinline__ void ast(float* p, float v) {
  __hip_atomic_store(p, v, __ATOMIC_RELAXED, __HIP_MEMORY_SCOPE_AGENT);
}
__device__ __forceinline__ float ald(const float* p) {
  return __hip_atomic_load(p, __ATOMIC_RELAXED, __HIP_MEMORY_SCOPE_AGENT);
}

struct MegaArgs {
  const float *f_atoms_sv, *f_bonds_sv;
  const int *a2b_sv, *b2a_sv, *b2revb_sv;
  const float *f_atoms_su, *f_bonds_su;
  const int *a2b_su, *b2a_su, *b2revb_su;
  const float *W_i, *W_h, *W_o, *b_o, *W_a1, *b_a1, *W_a2, *b_a2;
  float *out, *pmax, *psum, *rowS, *colS;
  unsigned* counter;
  unsigned short *bondsb, *a_in, *Wt_i, *Wt_h, *Wt_o, *Wt_a1sv, *Wt_a1su;
  unsigned short *msg, *X, *ahb, *U_b, *V_b, *inpB;
};

// ---- GEMM core: BM=128 BN=64 BK=64, 4 waves 2x2, dbuf LDS 48KB (verified) --
template<bool ADD_C, bool BIAS, bool RELU, bool RELUB, bool ST_B2>
__device__ __forceinline__ void gemm_core(char* smem,
    const unsigned short* __restrict__ A, const unsigned short* __restrict__ Bt,
    const unsigned short* __restrict__ CinB, const float* __restrict__ bias,
    unsigned short* __restrict__ outB, unsigned short* __restrict__ outB2,
    int N, int Kp, int bm, int bn) {
  unsigned short* As = (unsigned short*)smem;            // 2 x 8192 ushort
  unsigned short* Bs = (unsigned short*)(smem + 32768);  // 2 x 4096 ushort
  const int tid = threadIdx.x;
  const int lane = tid & 63;
  const int wave = tid >> 6;
  const int wm = (wave >> 1) * 64;
  const int wn = (wave & 1) * 32;

  f32x4 acc[4][2];
#pragma unroll
  for (int mf = 0; mf < 4; ++mf)
#pragma unroll
    for (int nf = 0; nf < 2; ++nf)
      acc[mf][nf] = f32x4{0.f, 0.f, 0.f, 0.f};

  auto stage = [&](int buf, int k0) {
#pragma unroll
    for (int i = 0; i < 4; ++i) {             // A: 128x64 = 1024 x 16B
      const int s = i * 256 + tid;
      const int row = s >> 3, sl = s & 7;
      const int gk = (sl ^ (row & 7)) << 3;
      const unsigned short* gp = A + (size_t)(bm + row) * Kp + k0 + gk;
      __builtin_amdgcn_global_load_lds(
          (const __attribute__((address_space(1))) void*)gp,
          (__attribute__((address_space(3))) void*)&As[buf * 8192 + s * 8], 16, 0, 0);
    }
#pragma unroll
    for (int i = 0; i < 2; ++i) {             // B: 64x64 = 512 x 16B
      const int s = i * 256 + tid;
      const int row = s >> 3, sl = s & 7;
      const int gk = (sl ^ (row & 7)) << 3;
      const unsigned short* gp = Bt + (size_t)(bn + row) * Kp + k0 + gk;
      __builtin_amdgcn_global_load_lds(
          (const __attribute__((address_space(1))) void*)gp,
          (__attribute__((address_space(3))) void*)&Bs[buf * 4096 + s * 8], 16, 0, 0);
    }
  };

  stage(0, 0);
  __syncthreads();
  const int nt = Kp >> 6;
  int cur = 0;
  for (int t = 0; t < nt; ++t) {
    if (t + 1 < nt) stage(cur ^ 1, (t + 1) << 6);
    const int lrow = lane & 15, lgrp = lane >> 4;
#pragma unroll
    for (int kk = 0; kk < 2; ++kk) {
      const int slot = kk * 4 + lgrp;
      bf16x8 af[4], bfr[2];
#pragma unroll
      for (int mf = 0; mf < 4; ++mf) {
        const int row = wm + mf * 16 + lrow;
        af[mf] = *reinterpret_cast<const bf16x8*>(&As[cur * 8192 + row * 64 + ((slot ^ (row & 7)) << 3)]);
      }
#pragma unroll
      for (int nf = 0; nf < 2; ++nf) {
        const int row = wn + nf * 16 + lrow;
        bfr[nf] = *reinterpret_cast<const bf16x8*>(&Bs[cur * 4096 + row * 64 + ((slot ^ (row & 7)) << 3)]);
      }
#pragma unroll
      for (int mf = 0; mf < 4; ++mf)
#pragma unroll
        for (int nf = 0; nf < 2; ++nf)
          acc[mf][nf] = __builtin_amdgcn_mfma_f32_16x16x32_bf16(af[mf], bfr[nf], acc[mf][nf], 0, 0, 0);
    }
    __syncthreads();
    cur ^= 1;
  }

  const int lrow = lane & 15, lgrp = lane >> 4;
#pragma unroll
  for (int mf = 0; mf < 4; ++mf)
#pragma unroll
    for (int nf = 0; nf < 2; ++nf)
#pragma unroll
      for (int i = 0; i < 4; ++i) {
        const int row = bm + wm + mf * 16 + lgrp * 4 + i;
        const int col = bn + wn + nf * 16 + lrow;
        const size_t idx = (size_t)row * N + col;
        float v = acc[mf][nf][i];
        if (ADD_C) v += bf2f(CinB[idx]);
        if (BIAS) { if (bias) v += bias[col]; }
        if (RELU) v = fmaxf(v, 0.f);
        if (ST_B2) outB2[idx] = f2bf(v);
        outB[idx] = RELUB ? f2bf(fmaxf(v, 0.f)) : f2bf(v);
      }
}

// ---- job bodies (hardware-verified R10/R11) ----
__device__ __forceinline__ void wconv_job(const MegaArgs& P, int j, float* T) {
  const float* src; unsigned short* dst; int K, N, stride, colOff, kt, t;
  if (j < 24)       { t = j;       src = P.W_i;  dst = P.Wt_i;    K = BFD; N = 512;  stride = KPAD; colOff = 0;    kt = 3; }
  else if (j < 88)  { t = j - 24;  src = P.W_h;  dst = P.Wt_h;    K = HD;  N = 512;  stride = HD;   colOff = 0;    kt = 8; }
  else if (j < 112) { t = j - 88;  src = P.W_o;  dst = P.Wt_o;    K = AF;  N = 512;  stride = AKP;  colOff = 0;    kt = 3; }
  else if (j < 176) { t = j - 112; src = P.W_o + (size_t)AF * HD; dst = P.Wt_o; K = HD; N = 512; stride = AKP; colOff = KPAD; kt = 8; }
  else if (j < 304) { t = j - 176; src = P.W_a1; dst = P.Wt_a1sv; K = HD;  N = 1024; stride = HD;   colOff = 0;    kt = 8; }
  else              { t = j - 304; src = P.W_a1 + (size_t)HD * 1024; dst = P.Wt_a1su; K = HD; N = 1024; stride = HD; colOff = 0; kt = 8; }
  const int tid = threadIdx.x;
  const int k0 = (t % kt) * 64, n0 = (t / kt) * 64;
  const int r = tid >> 2, c4 = (tid & 3) * 16;
  const int k = k0 + r;
#pragma unroll
  for (int q = 0; q < 16; ++q)
    T[(c4 + q) * 65 + r] = (k < K) ? src[(size_t)k * N + n0 + c4 + q] : 0.f;
  __syncthreads();
#pragma unroll
  for (int q = 0; q < 16; ++q)
    dst[(size_t)(n0 + r) * stride + colOff + k0 + c4 + q] = f2bf(T[r * 65 + c4 + q]);
}

__device__ __forceinline__ void act_job(const MegaArgs& P, int j) {
  const int tid = threadIdx.x;
  const float* src; unsigned short* dst; int K, stride, off;
  if (j < 288)      { src = P.f_bonds_sv; dst = P.bondsb;                        K = BFD; stride = KPAD; off = 0; }
  else if (j < 672) { src = P.f_bonds_su; dst = P.bondsb + (size_t)NB_SV * KPAD; K = BFD; stride = KPAD; off = 288; }
  else if (j < 816) { src = P.f_atoms_sv; dst = P.a_in;                          K = AF;  stride = AKP;  off = 672; }
  else              { src = P.f_atoms_su; dst = P.a_in + (size_t)NA_SV * AKP;    K = AF;  stride = AKP;  off = 816; }
  const int id = (j - off) * 256 + tid;
  const int r = id / 24;
  const int c8 = (id - r * 24) << 3;
  const float* s = src + (size_t)r * K;
  unsigned short o[8];
#pragma unroll
  for (int e = 0; e < 8; ++e) {
    const int kk = c8 + e;
    o[e] = (kk < K) ? f2bf(s[kk]) : (unsigned short)0;
  }
  *reinterpret_cast<uint4*>(&dst[(size_t)r * stride + c8]) = *reinterpret_cast<const uint4*>(o);
}

__device__ __forceinline__ void gather_x_job(const MegaArgs& P, int job) {
  const int idx = job * 256 + threadIdx.x;
  const int b = idx >> 6, c8 = (idx & 63) << 3;
  const int* a2b;
  int aL, rev, boff;
  if (b < NB_SV) { a2b = P.a2b_sv; aL = P.b2a_sv[b]; rev = P.b2revb_sv[b]; boff = 0; }
  else {
    const int bl = b - NB_SV;
    a2b = P.a2b_su; aL = P.b2a_su[bl]; rev = P.b2revb_su[bl] + NB_SV; boff = NB_SV;
  }
  float s[8] = {0.f, 0.f, 0.f, 0.f, 0.f, 0.f, 0.f, 0.f};
#pragma unroll
  for (int k = 0; k < 6; ++k) {
    const int bb = a2b[aL * 6 + k] + boff;
    const uint4 v = *reinterpret_cast<const uint4*>(P.msg + (size_t)bb * HD + c8);
    const unsigned short* p = reinterpret_cast<const unsigned short*>(&v);
#pragma unroll
    for (int e = 0; e < 8; ++e) s[e] += bf2f(p[e]);
  }
  const uint4 rv = *reinterpret_cast<const uint4*>(P.msg + (size_t)rev * HD + c8);
  const unsigned short* rp = reinterpret_cast<const unsigned short*>(&rv);
  unsigned short o[8];
#pragma unroll
  for (int e = 0; e < 8; ++e) o[e] = f2bf(s[e] - bf2f(rp[e]));
  *reinterpret_cast<uint4*>(P.X + (size_t)b * HD + c8) = *reinterpret_cast<const uint4*>(o);
}

__device__ __forceinline__ void gather_sum_job(const MegaArgs& P, int job) {
  const int idx = job * 256 + threadIdx.x;
  const int a = idx >> 6, c8 = (idx & 63) << 3;
  const int* a2b;
  int aL, boff;
  if (a < NA_SV) { a2b = P.a2b_sv; aL = a; boff = 0; }
  else { a2b = P.a2b_su; aL = a - NA_SV; boff = NB_SV; }
  float s[8] = {0.f, 0.f, 0.f, 0.f, 0.f, 0.f, 0.f, 0.f};
#pragma unroll
  for (int k = 0; k < 6; ++k) {
    const int bb = a2b[aL * 6 + k] + boff;
    const uint4 v = *reinterpret_cast<const uint4*>(P.msg + (size_t)bb * HD + c8);
    const unsigned short* p = reinterpret_cast<const unsigned short*>(&v);
#pragma unroll
    for (int e = 0; e < 8; ++e) s[e] += bf2f(p[e]);
  }
  unsigned short o[8];
#pragma unroll
  for (int e = 0; e < 8; ++e) o[e] = f2bf(s[e]);
  *reinterpret_cast<uint4*>(P.a_in + (size_t)a * AKP + KPAD + c8) = *reinterpret_cast<const uint4*>(o);
}

__device__ __forceinline__ void means_job(const MegaArgs& P, int b) {
  const int tid = threadIdx.x;
  const unsigned short* ahb_sv = P.ahb;
  const unsigned short* ahb_su = P.ahb + (size_t)NA_SV * HD;
  for (int c = tid; c < HD; c += 256) {
    float s = 0.f;
    for (int i = 0; i < ASV; ++i) s += bf2f(ahb_sv[((size_t)b * ASV + i) * HD + c]);
    P.out[(size_t)b * 2048 + c] = s * (1.0f / ASV);
  }
  for (int c = tid; c < HD; c += 256) {
    float s = 0.f;
    for (int j = 0; j < ASU; ++j) s += bf2f(ahb_su[((size_t)b * ASU + j) * HD + c]);
    P.out[(size_t)b * 2048 + 1536 + c] = s * (1.0f / ASU);
  }
}

// ================= kernels (10-launch pipeline) =================
__launch_bounds__(256)
__global__ void conv1_k(MegaArgs P) {   // Wt_i tiles (24) + bond act jobs (672) + zero counter
  __shared__ __align__(16) float T[64 * 65];
  const int j = blockIdx.x;
  if (j == 0 && threadIdx.x == 0)
    __hip_atomic_store(P.counter, 0u, __ATOMIC_RELAXED, __HIP_MEMORY_SCOPE_AGENT);
  if (j < 24) wconv_job(P, j, T);
  else act_job(P, j - 24);                // bond jobs 0..671
}
__launch_bounds__(256)
__global__ void wi_conv2_k(MegaArgs P) {  // W_i GEMM (448) + weight tiles (408) + atom act (336)
  __shared__ __align__(16) char smem[49152];
  const int bid = blockIdx.x;
  if (bid < 448)
    gemm_core<false, false, false, true, true>(smem, P.bondsb, P.Wt_i, nullptr, nullptr,
        P.msg, P.inpB, HD, KPAD, (bid % 56) * 128, (bid / 56) * 64);
  else if (bid < 856)
    wconv_job(P, 24 + (bid - 448), (float*)smem);
  else
    act_job(P, 672 + (bid - 856));
}
__launch_bounds__(256)
__global__ void gx_k(MegaArgs P) { gather_x_job(P, blockIdx.x); }
__launch_bounds__(256)
__global__ void wh_k(MegaArgs P) {
  __shared__ __align__(16) char smem[49152];
  gemm_core<true, false, true, false, false>(smem, P.X, P.Wt_h, P.inpB, nullptr,
      P.msg, nullptr, HD, HD, blockIdx.x * 128, blockIdx.y * 64);
}
__launch_bounds__(256)
__global__ void gs_k(MegaArgs P) { gather_sum_job(P, blockIdx.x); }
__launch_bounds__(256)
__global__ void wo_k(MegaArgs P) {
  __shared__ __align__(16) char smem[49152];
  gemm_core<false, true, true, false, false>(smem, P.a_in, P.Wt_o, nullptr, P.b_o,
      P.ahb, nullptr, HD, AKP, blockIdx.x * 128, blockIdx.y * 64);
}
__launch_bounds__(256)
__global__ void uv_means_k(MegaArgs P) {   // UV GEMM (448) + plain means (64)
  __shared__ __align__(16) char smem[49152];
  const int t = blockIdx.x;
  if (t < 192)
    gemm_core<false, true, false, false, false>(smem, P.ahb, P.Wt_a1sv, nullptr, P.b_a1,
        P.U_b, nullptr, 1024, HD, (t % 12) * 128, (t / 12) * 64);
  else if (t < 448) {
    const int tt = t - 192;
    gemm_core<false, true, false, false, false>(smem, P.ahb + (size_t)NA_SV * HD, P.Wt_a1su,
        nullptr, nullptr, P.V_b, nullptr, 1024, HD, (tt % 16) * 128, (tt / 16) * 64);
  } else
    means_job(P, t - 448);
}

// ---- fused score + combs: 512 blocks; blocks 0..63 finish with combs -------
// All cross-block data (pmax/psum/rowS/colS) moves via device-scope atomics
// (coherent across XCDs); plain stores would sit in the writer's L2.
__launch_bounds__(256)
__global__ void scorecombs_k(MegaArgs P) {
  __shared__ __align__(16) float sm[320];   // s_sc[96] / red[256] / att[56]
  const int bid = blockIdx.x;
  const int it = bid & 7;
  const int b = bid >> 3;
  const int tid = threadIdx.x;
  const int lane = tid & 63;
  const int wave = tid >> 6;

  // ---------- score phase (96 scores of (b, rows it*3..it*3+2)) ----------
  {
    float* s_sc = sm;
    const int i0 = it * 3;
    bf16x8 uf[3][2];
#pragma unroll
    for (int ii = 0; ii < 3; ++ii) {
      const unsigned short* up = P.U_b + (size_t)(b * ASV + i0 + ii) * 1024 + lane * 16;
      uf[ii][0] = *reinterpret_cast<const bf16x8*>(up);
      uf[ii][1] = *reinterpret_cast<const bf16x8*>(up + 8);
    }
    float wv[16];
#pragma unroll
    for (int q = 0; q < 4; ++q) {
      const float4 w4 = *reinterpret_cast<const float4*>(P.W_a2 + lane * 16 + q * 4);
      wv[q * 4] = w4.x; wv[q * 4 + 1] = w4.y; wv[q * 4 + 2] = w4.z; wv[q * 4 + 3] = w4.w;
    }
    const float bias = P.b_a2[0];
#pragma unroll
    for (int jj = 0; jj < 8; ++jj) {
      const int j = wave * 8 + jj;
      const unsigned short* vp = P.V_b + (size_t)(b * ASU + j) * 1024 + lane * 16;
      const bf16x8 v0 = *reinterpret_cast<const bf16x8*>(vp);
      const bf16x8 v1 = *reinterpret_cast<const bf16x8*>(vp + 8);
#pragma unroll
      for (int ii = 0; ii < 3; ++ii) {
        float s = 0.f;
#pragma unroll
        for (int e = 0; e < 8; ++e) {
          const float x0 = fmaxf((float)uf[ii][0][e] + (float)v0[e], 0.f);
          s = fmaf(x0, wv[e], s);
          const float x1 = fmaxf((float)uf[ii][1][e] + (float)v1[e], 0.f);
          s = fmaf(x1, wv[8 + e], s);
        }
#pragma unroll
        for (int off = 32; off; off >>= 1) s += __shfl_xor(s, off);
        if (lane == 0) s_sc[ii * 32 + j] = s + bias;
      }
    }
    __syncthreads();
    // wave 0: block max, then per-col sums (lanes 0..31) + row sums + psum
    if (wave == 0) {
      const float v0 = s_sc[lane];
      const float v1 = (lane < 32) ? s_sc[64 + lane] : -1e30f;
      float mx = fmaxf(v0, v1);
#pragma unroll
      for (int off = 32; off; off >>= 1) mx = fmaxf(mx, __shfl_xor(mx, off));
      float e0 = 0.f, e1 = 0.f, e2 = 0.f;
      if (lane < 32) {
        e0 = __expf(s_sc[lane] - mx);
        e1 = __expf(s_sc[32 + lane] - mx);
        e2 = __expf(s_sc[64 + lane] - mx);
        ast(&P.colS[(size_t)bid * 32 + lane], e0 + e1 + e2);
      }
      float r0 = e0, r1 = e1, r2 = e2;
#pragma unroll
      for (int off = 16; off; off >>= 1) {
        r0 += __shfl_xor(r0, off);
        r1 += __shfl_xor(r1, off);
        r2 += __shfl_xor(r2, off);
      }
      if (lane == 0) {
        ast(&P.pmax[bid], mx);
        ast(&P.psum[bid], r0 + r1 + r2);
        ast(&P.rowS[bid * 3 + 0], r0);
        ast(&P.rowS[bid * 3 + 1], r1);
        ast(&P.rowS[bid * 3 + 2], r2);
      }
    }
    __syncthreads();           // all atomic stores retired (vmcnt drained)
    if (tid == 0) {
      __threadfence();
      atomicAdd(P.counter, 1u);
    }
  }

  // ---------- combs phase: blocks 0..63 wait for all 512 publishes ----------
  if (bid >= 64) return;
  if (tid == 0) {
    while (__hip_atomic_load(P.counter, __ATOMIC_ACQUIRE, __HIP_MEMORY_SCOPE_AGENT) < 512u)
      __builtin_amdgcn_s_sleep(8);
  }
  __syncthreads();

  const int m = bid;           // molecule
  float* red = sm;             // 256
  // gmax over 512 block maxima
  float mx = -1e30f;
  for (int i = tid; i < 512; i += 256) mx = fmaxf(mx, ald(&P.pmax[i]));
  red[tid] = mx; __syncthreads();
  for (int s = 128; s; s >>= 1) {
    if (tid < s) red[tid] = fmaxf(red[tid], red[tid + s]);
    __syncthreads();
  }
  const float gmax = red[0];
  __syncthreads();
  float sum = 0.f;
  for (int i = tid; i < 512; i += 256) sum += ald(&P.psum[i]) * __expf(ald(&P.pmax[i]) - gmax);
  red[tid] = sum; __syncthreads();
  for (int s = 128; s; s >>= 1) {
    if (tid < s) red[tid] += red[tid + s];
    __syncthreads();
  }
  const float inv = 1.0f / red[0];
  __syncthreads();

  float* attRow = sm + 256;    // 24
  float* attCol = sm + 280;    // 32
  if (tid < ASV) {
    const int jb = m * 8 + tid / 3;
    attRow[tid] = ald(&P.rowS[jb * 3 + tid % 3]) * __expf(ald(&P.pmax[jb]) - gmax) * inv;
  }
  if (tid >= 64 && tid < 64 + ASU) {
    const int j = tid - 64;
    float s = 0.f;
    for (int itb = 0; itb < 8; ++itb) {
      const int jb = m * 8 + itb;
      s += ald(&P.colS[(size_t)jb * 32 + j]) * __expf(ald(&P.pmax[jb]) - gmax);
    }
    attCol[j] = s * inv;
  }
  __syncthreads();

  const float invP = 1.0f / (float)(ASV * ASU);
  const unsigned short* ahb_sv = P.ahb;
  const unsigned short* ahb_su = P.ahb + (size_t)NA_SV * HD;
  for (int c = tid; c < HD; c += 256) {
    float s_att = 0.f;
    for (int i = 0; i < ASV; ++i)
      s_att = fmaf(attRow[i], bf2f(ahb_sv[((size_t)m * ASV + i) * HD + c]), s_att);
    P.out[(size_t)m * 2048 + 512 + c] = s_att * invP;
  }
  for (int c = tid; c < HD; c += 256) {
    float s_att = 0.f;
    for (int j = 0; j < ASU; ++j)
      s_att = fmaf(attCol[j], bf2f(ahb_su[((size_t)m * ASU + j) * HD + c]), s_att);
    P.out[(size_t)m * 2048 + 1024 + c] = s_att * invP;
  }
}

extern "C" void kernel_launch(void* const* d_in, const int* in_sizes, int n_in,
                              void* d_out, int out_size, void* d_ws, size_t ws_size,
                              hipStream_t stream) {
  (void)in_sizes; (void)n_in; (void)out_size; (void)ws_size;
  MegaArgs P;
  P.f_atoms_sv = (const float*)d_in[0];
  P.f_bonds_sv = (const float*)d_in[1];
  P.a2b_sv     = (const int*)d_in[2];
  P.b2a_sv     = (const int*)d_in[3];
  P.b2revb_sv  = (const int*)d_in[4];
  P.f_atoms_su = (const float*)d_in[5];
  P.f_bonds_su = (const float*)d_in[6];
  P.a2b_su     = (const int*)d_in[7];
  P.b2a_su     = (const int*)d_in[8];
  P.b2revb_su  = (const int*)d_in[9];
  P.W_i  = (const float*)d_in[10];
  P.W_h  = (const float*)d_in[11];
  P.W_o  = (const float*)d_in[12];
  P.b_o  = (const float*)d_in[13];
  P.W_a1 = (const float*)d_in[14];
  P.b_a1 = (const float*)d_in[15];
  P.W_a2 = (const float*)d_in[16];
  P.b_a2 = (const float*)d_in[17];
  P.out  = (float*)d_out;

  float* f = (float*)d_ws;
  P.pmax = f;  f += 512;
  P.psum = f;  f += 512;
  P.rowS = f;  f += 512 * 3;
  P.colS = f;  f += 512 * 32;
  P.counter = (unsigned*)f;  f += 64;       // padded
  unsigned short* u = (unsigned short*)f;
  P.bondsb  = u;  u += (size_t)NBT * KPAD;
  P.a_in    = u;  u += (size_t)NAT * AKP;
  P.Wt_i    = u;  u += (size_t)HD * KPAD;
  P.Wt_h    = u;  u += (size_t)HD * HD;
  P.Wt_o    = u;  u += (size_t)HD * AKP;
  P.Wt_a1sv = u;  u += (size_t)1024 * HD;
  P.Wt_a1su = u;  u += (size_t)1024 * HD;
  P.msg     = u;  u += (size_t)NBT * HD;
  P.X       = u;  u += (size_t)NBT * HD;
  P.ahb     = u;  u += (size_t)NAT * HD;
  P.inpB    = u;  u += (size_t)NBT * HD;
  P.U_b = P.inpB;                              // inpB dead after depth loop
  P.V_b = P.U_b + (size_t)NA_SV * 1024;

  conv1_k<<<696, 256, 0, stream>>>(P);
  wi_conv2_k<<<1192, 256, 0, stream>>>(P);
  for (int d = 0; d < 2; ++d) {
    gx_k<<<1792, 256, 0, stream>>>(P);
    wh_k<<<dim3(56, 8), 256, 0, stream>>>(P);
  }
  gs_k<<<896, 256, 0, stream>>>(P);
  wo_k<<<dim3(28, 8), 256, 0, stream>>>(P);
  uv_means_k<<<512, 256, 0, stream>>>(P);
  scorecombs_k<<<512, 256, 0, stream>>>(P);
}

// Round 13
// 108.408 us; speedup vs baseline: 1.1497x; 1.1497x over previous
//
#include <hip/hip_runtime.h>

#define HD 512
#define B_MOL 64
#define ASV 24
#define ASU 32
#define AF 133
#define BFD 147
#define NA_SV (B_MOL*ASV)     // 1536
#define NB_SV (2*B_MOL*ASV)   // 3072
#define NA_SU (B_MOL*ASU)     // 2048
#define NB_SU (2*B_MOL*ASU)   // 4096
#define NBT (NB_SV+NB_SU)     // 7168
#define NAT (NA_SV+NA_SU)     // 3584
#define KPAD 192
#define AKP 704

typedef __bf16 bf16x8 __attribute__((ext_vector_type(8)));
typedef float f32x4 __attribute__((ext_vector_type(4)));

__device__ __forceinline__ unsigned short f2bf(float f) {
  unsigned u = __builtin_bit_cast(unsigned, f);
  unsigned r = u + 0x7fffu + ((u >> 16) & 1u);
  return (unsigned short)(r >> 16);
}
__device__ __forceinline__ float bf2f(unsigned short h) {
  unsigned u = ((unsigned)h) << 16;
  return __builtin_bit_cast(float, u);
}

struct MegaArgs {
  const float *f_atoms_sv, *f_bonds_sv;
  const int *a2b_sv, *b2a_sv, *b2revb_sv;
  const float *f_atoms_su, *f_bonds_su;
  const int *a2b_su, *b2a_su, *b2revb_su;
  const float *W_i, *W_h, *W_o, *b_o, *W_a1, *b_a1, *W_a2, *b_a2;
  float *out, *pmax, *psum, *rowS, *colS;
  unsigned short *bondsb, *a_in, *Wt_i, *Wt_h, *Wt_o, *Wt_a1sv, *Wt_a1su;
  unsigned short *msg, *X, *ahb, *U_b, *V_b, *inpB;
};

// ---- GEMM core: BM=128 BN=64 BK=64, 4 waves 2x2, dbuf LDS 48KB (verified) --
template<bool ADD_C, bool BIAS, bool RELU, bool RELUB, bool ST_B2>
__device__ __forceinline__ void gemm_core(char* smem,
    const unsigned short* __restrict__ A, const unsigned short* __restrict__ Bt,
    const unsigned short* __restrict__ CinB, const float* __restrict__ bias,
    unsigned short* __restrict__ outB, unsigned short* __restrict__ outB2,
    int N, int Kp, int bm, int bn) {
  unsigned short* As = (unsigned short*)smem;            // 2 x 8192 ushort
  unsigned short* Bs = (unsigned short*)(smem + 32768);  // 2 x 4096 ushort
  const int tid = threadIdx.x;
  const int lane = tid & 63;
  const int wave = tid >> 6;
  const int wm = (wave >> 1) * 64;
  const int wn = (wave & 1) * 32;

  f32x4 acc[4][2];
#pragma unroll
  for (int mf = 0; mf < 4; ++mf)
#pragma unroll
    for (int nf = 0; nf < 2; ++nf)
      acc[mf][nf] = f32x4{0.f, 0.f, 0.f, 0.f};

  auto stage = [&](int buf, int k0) {
#pragma unroll
    for (int i = 0; i < 4; ++i) {             // A: 128x64 = 1024 x 16B
      const int s = i * 256 + tid;
      const int row = s >> 3, sl = s & 7;
      const int gk = (sl ^ (row & 7)) << 3;
      const unsigned short* gp = A + (size_t)(bm + row) * Kp + k0 + gk;
      __builtin_amdgcn_global_load_lds(
          (const __attribute__((address_space(1))) void*)gp,
          (__attribute__((address_space(3))) void*)&As[buf * 8192 + s * 8], 16, 0, 0);
    }
#pragma unroll
    for (int i = 0; i < 2; ++i) {             // B: 64x64 = 512 x 16B
      const int s = i * 256 + tid;
      const int row = s >> 3, sl = s & 7;
      const int gk = (sl ^ (row & 7)) << 3;
      const unsigned short* gp = Bt + (size_t)(bn + row) * Kp + k0 + gk;
      __builtin_amdgcn_global_load_lds(
          (const __attribute__((address_space(1))) void*)gp,
          (__attribute__((address_space(3))) void*)&Bs[buf * 4096 + s * 8], 16, 0, 0);
    }
  };

  stage(0, 0);
  __syncthreads();
  const int nt = Kp >> 6;
  int cur = 0;
  for (int t = 0; t < nt; ++t) {
    if (t + 1 < nt) stage(cur ^ 1, (t + 1) << 6);
    const int lrow = lane & 15, lgrp = lane >> 4;
#pragma unroll
    for (int kk = 0; kk < 2; ++kk) {
      const int slot = kk * 4 + lgrp;
      bf16x8 af[4], bfr[2];
#pragma unroll
      for (int mf = 0; mf < 4; ++mf) {
        const int row = wm + mf * 16 + lrow;
        af[mf] = *reinterpret_cast<const bf16x8*>(&As[cur * 8192 + row * 64 + ((slot ^ (row & 7)) << 3)]);
      }
#pragma unroll
      for (int nf = 0; nf < 2; ++nf) {
        const int row = wn + nf * 16 + lrow;
        bfr[nf] = *reinterpret_cast<const bf16x8*>(&Bs[cur * 4096 + row * 64 + ((slot ^ (row & 7)) << 3)]);
      }
#pragma unroll
      for (int mf = 0; mf < 4; ++mf)
#pragma unroll
        for (int nf = 0; nf < 2; ++nf)
          acc[mf][nf] = __builtin_amdgcn_mfma_f32_16x16x32_bf16(af[mf], bfr[nf], acc[mf][nf], 0, 0, 0);
    }
    __syncthreads();
    cur ^= 1;
  }

  const int lrow = lane & 15, lgrp = lane >> 4;
#pragma unroll
  for (int mf = 0; mf < 4; ++mf)
#pragma unroll
    for (int nf = 0; nf < 2; ++nf)
#pragma unroll
      for (int i = 0; i < 4; ++i) {
        const int row = bm + wm + mf * 16 + lgrp * 4 + i;
        const int col = bn + wn + nf * 16 + lrow;
        const size_t idx = (size_t)row * N + col;
        float v = acc[mf][nf][i];
        if (ADD_C) v += bf2f(CinB[idx]);
        if (BIAS) { if (bias) v += bias[col]; }
        if (RELU) v = fmaxf(v, 0.f);
        if (ST_B2) outB2[idx] = f2bf(v);
        outB[idx] = RELUB ? f2bf(fmaxf(v, 0.f)) : f2bf(v);
      }
}

// ---- job bodies (hardware-verified R10/R11/R12) ----
__device__ __forceinline__ void wconv_job(const MegaArgs& P, int j, float* T) {
  const float* src; unsigned short* dst; int K, N, stride, colOff, kt, t;
  if (j < 24)       { t = j;       src = P.W_i;  dst = P.Wt_i;    K = BFD; N = 512;  stride = KPAD; colOff = 0;    kt = 3; }
  else if (j < 88)  { t = j - 24;  src = P.W_h;  dst = P.Wt_h;    K = HD;  N = 512;  stride = HD;   colOff = 0;    kt = 8; }
  else if (j < 112) { t = j - 88;  src = P.W_o;  dst = P.Wt_o;    K = AF;  N = 512;  stride = AKP;  colOff = 0;    kt = 3; }
  else if (j < 176) { t = j - 112; src = P.W_o + (size_t)AF * HD; dst = P.Wt_o; K = HD; N = 512; stride = AKP; colOff = KPAD; kt = 8; }
  else if (j < 304) { t = j - 176; src = P.W_a1; dst = P.Wt_a1sv; K = HD;  N = 1024; stride = HD;   colOff = 0;    kt = 8; }
  else              { t = j - 304; src = P.W_a1 + (size_t)HD * 1024; dst = P.Wt_a1su; K = HD; N = 1024; stride = HD; colOff = 0; kt = 8; }
  const int tid = threadIdx.x;
  const int k0 = (t % kt) * 64, n0 = (t / kt) * 64;
  const int r = tid >> 2, c4 = (tid & 3) * 16;
  const int k = k0 + r;
#pragma unroll
  for (int q = 0; q < 16; ++q)
    T[(c4 + q) * 65 + r] = (k < K) ? src[(size_t)k * N + n0 + c4 + q] : 0.f;
  __syncthreads();
#pragma unroll
  for (int q = 0; q < 16; ++q)
    dst[(size_t)(n0 + r) * stride + colOff + k0 + c4 + q] = f2bf(T[r * 65 + c4 + q]);
}

__device__ __forceinline__ void act_job(const MegaArgs& P, int j) {
  const int tid = threadIdx.x;
  const float* src; unsigned short* dst; int K, stride, off;
  if (j < 288)      { src = P.f_bonds_sv; dst = P.bondsb;                        K = BFD; stride = KPAD; off = 0; }
  else if (j < 672) { src = P.f_bonds_su; dst = P.bondsb + (size_t)NB_SV * KPAD; K = BFD; stride = KPAD; off = 288; }
  else if (j < 816) { src = P.f_atoms_sv; dst = P.a_in;                          K = AF;  stride = AKP;  off = 672; }
  else              { src = P.f_atoms_su; dst = P.a_in + (size_t)NA_SV * AKP;    K = AF;  stride = AKP;  off = 816; }
  const int id = (j - off) * 256 + tid;
  const int r = id / 24;
  const int c8 = (id - r * 24) << 3;
  const float* s = src + (size_t)r * K;
  unsigned short o[8];
#pragma unroll
  for (int e = 0; e < 8; ++e) {
    const int kk = c8 + e;
    o[e] = (kk < K) ? f2bf(s[kk]) : (unsigned short)0;
  }
  *reinterpret_cast<uint4*>(&dst[(size_t)r * stride + c8]) = *reinterpret_cast<const uint4*>(o);
}

__device__ __forceinline__ void gather_x_job(const MegaArgs& P, int job) {
  const int idx = job * 256 + threadIdx.x;
  const int b = idx >> 6, c8 = (idx & 63) << 3;
  const int* a2b;
  int aL, rev, boff;
  if (b < NB_SV) { a2b = P.a2b_sv; aL = P.b2a_sv[b]; rev = P.b2revb_sv[b]; boff = 0; }
  else {
    const int bl = b - NB_SV;
    a2b = P.a2b_su; aL = P.b2a_su[bl]; rev = P.b2revb_su[bl] + NB_SV; boff = NB_SV;
  }
  float s[8] = {0.f, 0.f, 0.f, 0.f, 0.f, 0.f, 0.f, 0.f};
#pragma unroll
  for (int k = 0; k < 6; ++k) {
    const int bb = a2b[aL * 6 + k] + boff;
    const uint4 v = *reinterpret_cast<const uint4*>(P.msg + (size_t)bb * HD + c8);
    const unsigned short* p = reinterpret_cast<const unsigned short*>(&v);
#pragma unroll
    for (int e = 0; e < 8; ++e) s[e] += bf2f(p[e]);
  }
  const uint4 rv = *reinterpret_cast<const uint4*>(P.msg + (size_t)rev * HD + c8);
  const unsigned short* rp = reinterpret_cast<const unsigned short*>(&rv);
  unsigned short o[8];
#pragma unroll
  for (int e = 0; e < 8; ++e) o[e] = f2bf(s[e] - bf2f(rp[e]));
  *reinterpret_cast<uint4*>(P.X + (size_t)b * HD + c8) = *reinterpret_cast<const uint4*>(o);
}

__device__ __forceinline__ void gather_sum_job(const MegaArgs& P, int job) {
  const int idx = job * 256 + threadIdx.x;
  const int a = idx >> 6, c8 = (idx & 63) << 3;
  const int* a2b;
  int aL, boff;
  if (a < NA_SV) { a2b = P.a2b_sv; aL = a; boff = 0; }
  else { a2b = P.a2b_su; aL = a - NA_SV; boff = NB_SV; }
  float s[8] = {0.f, 0.f, 0.f, 0.f, 0.f, 0.f, 0.f, 0.f};
#pragma unroll
  for (int k = 0; k < 6; ++k) {
    const int bb = a2b[aL * 6 + k] + boff;
    const uint4 v = *reinterpret_cast<const uint4*>(P.msg + (size_t)bb * HD + c8);
    const unsigned short* p = reinterpret_cast<const unsigned short*>(&v);
#pragma unroll
    for (int e = 0; e < 8; ++e) s[e] += bf2f(p[e]);
  }
  unsigned short o[8];
#pragma unroll
  for (int e = 0; e < 8; ++e) o[e] = f2bf(s[e]);
  *reinterpret_cast<uint4*>(P.a_in + (size_t)a * AKP + KPAD + c8) = *reinterpret_cast<const uint4*>(o);
}

__device__ __forceinline__ void means_job(const MegaArgs& P, int b) {
  const int tid = threadIdx.x;
  const unsigned short* ahb_sv = P.ahb;
  const unsigned short* ahb_su = P.ahb + (size_t)NA_SV * HD;
  for (int c = tid; c < HD; c += 256) {
    float s = 0.f;
    for (int i = 0; i < ASV; ++i) s += bf2f(ahb_sv[((size_t)b * ASV + i) * HD + c]);
    P.out[(size_t)b * 2048 + c] = s * (1.0f / ASV);
  }
  for (int c = tid; c < HD; c += 256) {
    float s = 0.f;
    for (int j = 0; j < ASU; ++j) s += bf2f(ahb_su[((size_t)b * ASU + j) * HD + c]);
    P.out[(size_t)b * 2048 + 1536 + c] = s * (1.0f / ASU);
  }
}

// ================= kernels (11-launch pipeline) =================
__launch_bounds__(256)
__global__ void conv1_k(MegaArgs P) {   // Wt_i tiles (24) + bond act jobs (672)
  __shared__ __align__(16) float T[64 * 65];
  const int j = blockIdx.x;
  if (j < 24) wconv_job(P, j, T);
  else act_job(P, j - 24);                // bond jobs 0..671
}
__launch_bounds__(256)
__global__ void wi_conv2_k(MegaArgs P) {  // W_i GEMM (448) + weight tiles (408) + atom act (336)
  __shared__ __align__(16) char smem[49152];
  const int bid = blockIdx.x;
  if (bid < 448)
    gemm_core<false, false, false, true, true>(smem, P.bondsb, P.Wt_i, nullptr, nullptr,
        P.msg, P.inpB, HD, KPAD, (bid % 56) * 128, (bid / 56) * 64);
  else if (bid < 856)
    wconv_job(P, 24 + (bid - 448), (float*)smem);
  else
    act_job(P, 672 + (bid - 856));
}
__launch_bounds__(256)
__global__ void gx_k(MegaArgs P) { gather_x_job(P, blockIdx.x); }
__launch_bounds__(256)
__global__ void wh_k(MegaArgs P) {
  __shared__ __align__(16) char smem[49152];
  gemm_core<true, false, true, false, false>(smem, P.X, P.Wt_h, P.inpB, nullptr,
      P.msg, nullptr, HD, HD, blockIdx.x * 128, blockIdx.y * 64);
}
__launch_bounds__(256)
__global__ void gs_k(MegaArgs P) { gather_sum_job(P, blockIdx.x); }
__launch_bounds__(256)
__global__ void wo_k(MegaArgs P) {
  __shared__ __align__(16) char smem[49152];
  gemm_core<false, true, true, false, false>(smem, P.a_in, P.Wt_o, nullptr, P.b_o,
      P.ahb, nullptr, HD, AKP, blockIdx.x * 128, blockIdx.y * 64);
}
__launch_bounds__(256)
__global__ void uv_means_k(MegaArgs P) {   // UV GEMM (448) + plain means (64)
  __shared__ __align__(16) char smem[49152];
  const int t = blockIdx.x;
  if (t < 192)
    gemm_core<false, true, false, false, false>(smem, P.ahb, P.Wt_a1sv, nullptr, P.b_a1,
        P.U_b, nullptr, 1024, HD, (t % 12) * 128, (t / 12) * 64);
  else if (t < 448) {
    const int tt = t - 192;
    gemm_core<false, true, false, false, false>(smem, P.ahb + (size_t)NA_SV * HD, P.Wt_a1su,
        nullptr, nullptr, P.V_b, nullptr, 1024, HD, (tt % 16) * 128, (tt / 16) * 64);
  } else
    means_job(P, t - 448);
}

// ---- score: 512 blocks (it 0..7 x mol); publishes pmax/psum/rowS/colS ------
// (plain stores; the kernel-launch boundary provides cross-XCD coherence,
//  which R10/R12 measured to be far cheaper than any in-kernel global sync)
__launch_bounds__(256)
__global__ void score_k(MegaArgs P) {
  __shared__ float s_sc[96];
  const int bid = blockIdx.x;
  const int it = bid & 7;
  const int b = bid >> 3;
  const int tid = threadIdx.x;
  const int lane = tid & 63;
  const int wave = tid >> 6;

  const int i0 = it * 3;
  bf16x8 uf[3][2];
#pragma unroll
  for (int ii = 0; ii < 3; ++ii) {
    const unsigned short* up = P.U_b + (size_t)(b * ASV + i0 + ii) * 1024 + lane * 16;
    uf[ii][0] = *reinterpret_cast<const bf16x8*>(up);
    uf[ii][1] = *reinterpret_cast<const bf16x8*>(up + 8);
  }
  float wv[16];
#pragma unroll
  for (int q = 0; q < 4; ++q) {
    const float4 w4 = *reinterpret_cast<const float4*>(P.W_a2 + lane * 16 + q * 4);
    wv[q * 4] = w4.x; wv[q * 4 + 1] = w4.y; wv[q * 4 + 2] = w4.z; wv[q * 4 + 3] = w4.w;
  }
  const float bias = P.b_a2[0];
#pragma unroll
  for (int jj = 0; jj < 8; ++jj) {
    const int j = wave * 8 + jj;
    const unsigned short* vp = P.V_b + (size_t)(b * ASU + j) * 1024 + lane * 16;
    const bf16x8 v0 = *reinterpret_cast<const bf16x8*>(vp);
    const bf16x8 v1 = *reinterpret_cast<const bf16x8*>(vp + 8);
#pragma unroll
    for (int ii = 0; ii < 3; ++ii) {
      float s = 0.f;
#pragma unroll
      for (int e = 0; e < 8; ++e) {
        const float x0 = fmaxf((float)uf[ii][0][e] + (float)v0[e], 0.f);
        s = fmaf(x0, wv[e], s);
        const float x1 = fmaxf((float)uf[ii][1][e] + (float)v1[e], 0.f);
        s = fmaf(x1, wv[8 + e], s);
      }
#pragma unroll
      for (int off = 32; off; off >>= 1) s += __shfl_xor(s, off);
      if (lane == 0) s_sc[ii * 32 + j] = s + bias;
    }
  }
  __syncthreads();
  // wave 0: block max; per-col partial sums (lanes 0..31); row sums; psum
  if (wave == 0) {
    const float v0 = s_sc[lane];
    const float v1 = (lane < 32) ? s_sc[64 + lane] : -1e30f;
    float mx = fmaxf(v0, v1);
#pragma unroll
    for (int off = 32; off; off >>= 1) mx = fmaxf(mx, __shfl_xor(mx, off));
    float e0 = 0.f, e1 = 0.f, e2 = 0.f;
    if (lane < 32) {
      e0 = __expf(s_sc[lane] - mx);
      e1 = __expf(s_sc[32 + lane] - mx);
      e2 = __expf(s_sc[64 + lane] - mx);
      P.colS[(size_t)bid * 32 + lane] = e0 + e1 + e2;
    }
    float r0 = e0, r1 = e1, r2 = e2;
#pragma unroll
    for (int off = 16; off; off >>= 1) {
      r0 += __shfl_xor(r0, off);
      r1 += __shfl_xor(r1, off);
      r2 += __shfl_xor(r2, off);
    }
    if (lane == 0) {
      P.pmax[bid] = mx;
      P.psum[bid] = r0 + r1 + r2;
      P.rowS[bid * 3 + 0] = r0;
      P.rowS[bid * 3 + 1] = r1;
      P.rowS[bid * 3 + 2] = r2;
    }
  }
}

// ---- combs: 64 blocks; finalize softmax from 512 blocks' partials ----------
__launch_bounds__(256)
__global__ void combs_k(MegaArgs P) {
  __shared__ float sm[320];    // red[256] | attRow[24] | attCol[32]
  const int m = blockIdx.x;
  const int tid = threadIdx.x;
  float* red = sm;
  // gmax over 512 block maxima
  float mx = -1e30f;
  for (int i = tid; i < 512; i += 256) mx = fmaxf(mx, P.pmax[i]);
  red[tid] = mx; __syncthreads();
  for (int s = 128; s; s >>= 1) {
    if (tid < s) red[tid] = fmaxf(red[tid], red[tid + s]);
    __syncthreads();
  }
  const float gmax = red[0];
  __syncthreads();
  float sum = 0.f;
  for (int i = tid; i < 512; i += 256) sum += P.psum[i] * __expf(P.pmax[i] - gmax);
  red[tid] = sum; __syncthreads();
  for (int s = 128; s; s >>= 1) {
    if (tid < s) red[tid] += red[tid + s];
    __syncthreads();
  }
  const float inv = 1.0f / red[0];
  __syncthreads();

  float* attRow = sm + 256;    // 24
  float* attCol = sm + 280;    // 32
  if (tid < ASV) {
    const int jb = m * 8 + tid / 3;
    attRow[tid] = P.rowS[jb * 3 + tid % 3] * __expf(P.pmax[jb] - gmax) * inv;
  }
  if (tid >= 64 && tid < 64 + ASU) {
    const int j = tid - 64;
    float s = 0.f;
    for (int itb = 0; itb < 8; ++itb) {
      const int jb = m * 8 + itb;
      s += P.colS[(size_t)jb * 32 + j] * __expf(P.pmax[jb] - gmax);
    }
    attCol[j] = s * inv;
  }
  __syncthreads();

  const float invP = 1.0f / (float)(ASV * ASU);
  const unsigned short* ahb_sv = P.ahb;
  const unsigned short* ahb_su = P.ahb + (size_t)NA_SV * HD;
  for (int c = tid; c < HD; c += 256) {
    float s_att = 0.f;
    for (int i = 0; i < ASV; ++i)
      s_att = fmaf(attRow[i], bf2f(ahb_sv[((size_t)m * ASV + i) * HD + c]), s_att);
    P.out[(size_t)m * 2048 + 512 + c] = s_att * invP;
  }
  for (int c = tid; c < HD; c += 256) {
    float s_att = 0.f;
    for (int j = 0; j < ASU; ++j)
      s_att = fmaf(attCol[j], bf2f(ahb_su[((size_t)m * ASU + j) * HD + c]), s_att);
    P.out[(size_t)m * 2048 + 1024 + c] = s_att * invP;
  }
}

extern "C" void kernel_launch(void* const* d_in, const int* in_sizes, int n_in,
                              void* d_out, int out_size, void* d_ws, size_t ws_size,
                              hipStream_t stream) {
  (void)in_sizes; (void)n_in; (void)out_size; (void)ws_size;
  MegaArgs P;
  P.f_atoms_sv = (const float*)d_in[0];
  P.f_bonds_sv = (const float*)d_in[1];
  P.a2b_sv     = (const int*)d_in[2];
  P.b2a_sv     = (const int*)d_in[3];
  P.b2revb_sv  = (const int*)d_in[4];
  P.f_atoms_su = (const float*)d_in[5];
  P.f_bonds_su = (const float*)d_in[6];
  P.a2b_su     = (const int*)d_in[7];
  P.b2a_su     = (const int*)d_in[8];
  P.b2revb_su  = (const int*)d_in[9];
  P.W_i  = (const float*)d_in[10];
  P.W_h  = (const float*)d_in[11];
  P.W_o  = (const float*)d_in[12];
  P.b_o  = (const float*)d_in[13];
  P.W_a1 = (const float*)d_in[14];
  P.b_a1 = (const float*)d_in[15];
  P.W_a2 = (const float*)d_in[16];
  P.b_a2 = (const float*)d_in[17];
  P.out  = (float*)d_out;

  float* f = (float*)d_ws;
  P.pmax = f;  f += 512;
  P.psum = f;  f += 512;
  P.rowS = f;  f += 512 * 3;
  P.colS = f;  f += 512 * 32;
  unsigned short* u = (unsigned short*)f;
  P.bondsb  = u;  u += (size_t)NBT * KPAD;
  P.a_in    = u;  u += (size_t)NAT * AKP;
  P.Wt_i    = u;  u += (size_t)HD * KPAD;
  P.Wt_h    = u;  u += (size_t)HD * HD;
  P.Wt_o    = u;  u += (size_t)HD * AKP;
  P.Wt_a1sv = u;  u += (size_t)1024 * HD;
  P.Wt_a1su = u;  u += (size_t)1024 * HD;
  P.msg     = u;  u += (size_t)NBT * HD;
  P.X       = u;  u += (size_t)NBT * HD;
  P.ahb     = u;  u += (size_t)NAT * HD;
  P.inpB    = u;  u += (size_t)NBT * HD;
  P.U_b = P.inpB;                              // inpB dead after depth loop
  P.V_b = P.U_b + (size_t)NA_SV * 1024;

  conv1_k<<<696, 256, 0, stream>>>(P);
  wi_conv2_k<<<1192, 256, 0, stream>>>(P);
  for (int d = 0; d < 2; ++d) {
    gx_k<<<1792, 256, 0, stream>>>(P);
    wh_k<<<dim3(56, 8), 256, 0, stream>>>(P);
  }
  gs_k<<<896, 256, 0, stream>>>(P);
  wo_k<<<dim3(28, 8), 256, 0, stream>>>(P);
  uv_means_k<<<512, 256, 0, stream>>>(P);
  score_k<<<512, 256, 0, stream>>>(P);
  combs_k<<<64, 256, 0, stream>>>(P);
}